// Round 2
// 364.454 us; speedup vs baseline: 1.0350x; 1.0350x over previous
//
#include <hip/hip_runtime.h>

// x_t = a_t * x_{t-1} + u_t ; B=8, T=4096, D=1024, fp32.
// 3-pass chunked scan.
// R3: passes 1/3 rebuilt around 8-timestep load batches (16 independent
// global_load_dwordx4 in flight per wave, 16 KB/wave) after R2's 2-deep
// pipeline collapsed to VGPR=32 / 2 loads in flight (1.35 TB/s HBM, 1.3%
// VALUBusy => pure latency-bound). Non-temporal stores for `out` so pass-3
// streaming writes don't evict the LLC-warm a/u lines (a+u = 268 MB ~ LLC).
// R4: fix compile — __builtin_nontemporal_store needs a native vector type,
// not HIP_vector_type float4; bit-cast via ext_vector_type(4) float.
#define BB 8
#define TT 4096
#define DD 1024
#define SS 128            // segments along T
#define TSEG (TT / SS)    // 32 timesteps per segment
#define STR (DD / 4)      // float4 row stride
#define CH 8              // timesteps per load batch (16 float4 loads)

typedef float natf4 __attribute__((ext_vector_type(4)));

static __device__ __forceinline__ float4 ffma4(const float4 a, const float4 x,
                                               const float4 u) {
  return make_float4(fmaf(a.x, x.x, u.x), fmaf(a.y, x.y, u.y),
                     fmaf(a.z, x.z, u.z), fmaf(a.w, x.w, u.w));
}
static __device__ __forceinline__ float4 fmul4(const float4 a, const float4 b) {
  return make_float4(a.x * b.x, a.y * b.y, a.z * b.z, a.w * b.w);
}
static __device__ __forceinline__ void nt_store4(float4* p, const float4 v) {
  natf4 nv;
  nv.x = v.x; nv.y = v.y; nv.z = v.z; nv.w = v.w;
  __builtin_nontemporal_store(nv, (natf4*)p);
}

// ---------------------------------------------------------------------------
// Pass 1: per-segment affine summary (A = prod a, U = zero-init scan).
// Block = one (b, s); thread = 4 channels. Loads batched CH timesteps deep:
// 16 independent dwordx4 loads issued back-to-back, ONE vmcnt wait per chunk,
// then 8 serial chain steps. VGPR ~90 (5 waves/SIMD, grid supplies 4).
// ---------------------------------------------------------------------------
__global__ __launch_bounds__(256) void seg_reduce(
    const float* __restrict__ a, const float* __restrict__ u,
    float* __restrict__ wsA, float* __restrict__ wsU) {
  const int b = blockIdx.x >> 7;        // / SS
  const int s = blockIdx.x & (SS - 1);
  const int d4 = threadIdx.x << 2;

  const size_t base = ((size_t)b * TT + (size_t)s * TSEG) * DD + d4;
  const float4* __restrict__ ap = (const float4*)(a + base);
  const float4* __restrict__ up = (const float4*)(u + base);

  float4 A = make_float4(1.f, 1.f, 1.f, 1.f);
  float4 U = make_float4(0.f, 0.f, 0.f, 0.f);

#pragma unroll 1
  for (int tb = 0; tb < TSEG; tb += CH) {
    float4 av[CH], uv[CH];
#pragma unroll
    for (int k = 0; k < CH; ++k) {
      av[k] = ap[(size_t)(tb + k) * STR];
      uv[k] = up[(size_t)(tb + k) * STR];
    }
#pragma unroll
    for (int k = 0; k < CH; ++k) {
      U = ffma4(av[k], U, uv[k]);
      A = fmul4(A, av[k]);
    }
  }

  const size_t w = ((size_t)b * SS + s) * DD + d4;
  *(float4*)(wsA + w) = A;
  *(float4*)(wsU + w) = U;
}

// ---------------------------------------------------------------------------
// Pass 2: scan across segment summaries. Block = 64 channels x all SS segments
// staged in LDS (coalesced 256B global loads). Wave w composes segment chunk
// [32w, 32w+32) per channel, cross-wave prefix via LDS, then replays to emit
// xstart[b][s][d] (state entering each segment). Serial depth ~70 FMA.
// (Unchanged — small fraction of total time.)
// ---------------------------------------------------------------------------
__global__ __launch_bounds__(256) void seg_scan(
    const float* __restrict__ x0, const float* __restrict__ wsA,
    const float* __restrict__ wsU, float* __restrict__ xstart) {
  __shared__ float ldsA[SS * 64];       // [s][ch] : 32 KiB
  __shared__ float ldsU[SS * 64];       // 32 KiB
  __shared__ float wsumA[4][64];        // per-wave chunk transform
  __shared__ float wsumU[4][64];

  const int b  = blockIdx.x >> 4;       // 16 channel-groups per b
  const int d0 = (blockIdx.x & 15) << 6;
  const int ch = threadIdx.x & 63;
  const int wv = threadIdx.x >> 6;      // 0..3

  // stage summaries: wave-coalesced (fixed s, 64 consecutive d per instr)
#pragma unroll 8
  for (int it = 0; it < SS / 4; ++it) {
    const int s = (it << 2) + wv;
    const size_t g = ((size_t)b * SS + s) * DD + d0 + ch;
    ldsA[s * 64 + ch] = wsA[g];
    ldsU[s * 64 + ch] = wsU[g];
  }
  __syncthreads();

  // wave-chunk compose: segments [32w, 32w+32)
  float Ac = 1.f, Uc = 0.f;
  const int s0 = wv * (SS / 4);
#pragma unroll 8
  for (int k = 0; k < SS / 4; ++k) {
    const float As = ldsA[(s0 + k) * 64 + ch];
    const float Us = ldsU[(s0 + k) * 64 + ch];
    Uc = fmaf(As, Uc, Us);
    Ac *= As;
  }
  wsumA[wv][ch] = Ac;
  wsumU[wv][ch] = Uc;
  __syncthreads();

  // entry state for this wave's chunk: apply earlier chunks to x0 in order
  float x = x0[(size_t)b * DD + d0 + ch];
  for (int w2 = 0; w2 < wv; ++w2)
    x = fmaf(wsumA[w2][ch], x, wsumU[w2][ch]);

  // replay: emit state entering each segment (coalesced 256B stores)
#pragma unroll 8
  for (int k = 0; k < SS / 4; ++k) {
    const int s = s0 + k;
    xstart[((size_t)b * SS + s) * DD + d0 + ch] = x;
    x = fmaf(ldsA[s * 64 + ch], x, ldsU[s * 64 + ch]);
  }
}

// ---------------------------------------------------------------------------
// Pass 3: replay each segment from its entry state; same batched-load scheme
// as pass 1. Output stores are non-temporal: `out` is write-once, and keeping
// it out of the LLC preserves the a/u lines pass 1 just warmed.
// ---------------------------------------------------------------------------
__global__ __launch_bounds__(256) void seg_apply(
    const float* __restrict__ a, const float* __restrict__ u,
    const float* __restrict__ xstart, float* __restrict__ out) {
  const int b = blockIdx.x >> 7;
  const int s = blockIdx.x & (SS - 1);
  const int d4 = threadIdx.x << 2;

  const size_t base = ((size_t)b * TT + (size_t)s * TSEG) * DD + d4;
  const float4* __restrict__ ap = (const float4*)(a + base);
  const float4* __restrict__ up = (const float4*)(u + base);
  float4* __restrict__ op = (float4*)(out + base);

  const size_t w = ((size_t)b * SS + s) * DD + d4;
  float4 x = *(const float4*)(xstart + w);

#pragma unroll 1
  for (int tb = 0; tb < TSEG; tb += CH) {
    float4 av[CH], uv[CH];
#pragma unroll
    for (int k = 0; k < CH; ++k) {
      av[k] = ap[(size_t)(tb + k) * STR];
      uv[k] = up[(size_t)(tb + k) * STR];
    }
#pragma unroll
    for (int k = 0; k < CH; ++k) {
      x = ffma4(av[k], x, uv[k]);
      nt_store4(op + (size_t)(tb + k) * STR, x);
    }
  }
}

extern "C" void kernel_launch(void* const* d_in, const int* in_sizes, int n_in,
                              void* d_out, int out_size, void* d_ws, size_t ws_size,
                              hipStream_t stream) {
  const float* x0 = (const float*)d_in[0];  // [B, D]
  const float* a  = (const float*)d_in[1];  // [B, T, D]
  const float* u  = (const float*)d_in[2];  // [B, T, D]
  float* out = (float*)d_out;               // [B, T, D]

  const size_t seg_elems = (size_t)BB * SS * DD;  // 1M floats = 4 MiB
  float* wsA    = (float*)d_ws;
  float* wsU    = wsA + seg_elems;
  float* xstart = wsU + seg_elems;

  seg_reduce<<<BB * SS, 256, 0, stream>>>(a, u, wsA, wsU);
  seg_scan<<<BB * (DD / 64), 256, 0, stream>>>(x0, wsA, wsU, xstart);
  seg_apply<<<BB * SS, 256, 0, stream>>>(a, u, xstart, out);
}